// Round 4
// baseline (2408.576 us; speedup 1.0000x reference)
//
#include <hip/hip_runtime.h>
#include <cstdint>
#include <cstddef>
#include <cstdio>

#define B_   4
#define L_   4096
#define D_   1024
#define H_   16
#define BS_  64
#define HD_  64
#define NB_  64
#define SCALE_   0.125f
#define INV_TEMP (1.0f/0.7f)

typedef unsigned short bf16_t;

__device__ __forceinline__ float b2f(bf16_t u) {
    union { unsigned int i; float f; } c; c.i = ((unsigned int)u) << 16; return c.f;
}
__device__ __forceinline__ bf16_t f2b(float f) {
    union { float f; unsigned int i; } c; c.f = f;
    unsigned int r = c.i + 0x7FFFu + ((c.i >> 16) & 1u);   // RNE
    return (bf16_t)(r >> 16);
}

// vectorized 4-element loads promoted to fp32
__device__ __forceinline__ float4 load4(const float* p) { return *(const float4*)p; }
__device__ __forceinline__ float4 load4(const bf16_t* p) {
    ushort4 u = *(const ushort4*)p;
    return float4{b2f(u.x), b2f(u.y), b2f(u.z), b2f(u.w)};
}
// vectorized 4-element stores from fp32
__device__ __forceinline__ void store4(float* p, float4 v) { *(float4*)p = v; }
__device__ __forceinline__ void store4(bf16_t* p, float4 v) {
    ushort4 o = {f2b(v.x), f2b(v.y), f2b(v.z), f2b(v.w)};
    *(ushort4*)p = o;
}

// ---------------------------------------------------------------------------
// GEMM: C[M,N] = A[M,K] @ B[K,N] + bias[N];  A/B/C dtypes templated.
// 64x64 tile, BK=16, 16x16 threads, 4x4 microtile. All dims divisible.
// ---------------------------------------------------------------------------
template<typename TA, typename TB, typename TC>
__global__ __launch_bounds__(256) void gemm_bias_kernel(
    const TA* __restrict__ A, const TB* __restrict__ Bm,
    const float* __restrict__ bias, TC* __restrict__ C,
    int M, int N, int K)
{
    __shared__ float As[16][68];   // [k][m]
    __shared__ float Bs[16][68];   // [k][n]
    const int tx = threadIdx.x, ty = threadIdx.y;
    const int tid = ty * 16 + tx;
    const int row0 = blockIdx.y * 64, col0 = blockIdx.x * 64;

    const int ar = tid >> 2;          // 0..63 (A tile row)
    const int ak = (tid & 3) * 4;     // 0,4,8,12 (A tile k)
    const int bk = tid >> 4;          // 0..15 (B tile k)
    const int bn = (tid & 15) * 4;    // 0..60 (B tile col)

    float acc[4][4] = {};

    for (int k0 = 0; k0 < K; k0 += 16) {
        float4 av = load4(A  + (size_t)(row0 + ar) * K + k0 + ak);
        float4 bv = load4(Bm + (size_t)(k0 + bk) * N + col0 + bn);
        As[ak + 0][ar] = av.x; As[ak + 1][ar] = av.y;
        As[ak + 2][ar] = av.z; As[ak + 3][ar] = av.w;
        *(float4*)&Bs[bk][bn] = bv;
        __syncthreads();
        #pragma unroll
        for (int kk = 0; kk < 16; ++kk) {
            float4 a4 = *(const float4*)&As[kk][ty * 4];
            float4 b4 = *(const float4*)&Bs[kk][tx * 4];
            float a[4] = {a4.x, a4.y, a4.z, a4.w};
            float b[4] = {b4.x, b4.y, b4.z, b4.w};
            #pragma unroll
            for (int i = 0; i < 4; ++i)
                #pragma unroll
                for (int j = 0; j < 4; ++j)
                    acc[i][j] += a[i] * b[j];
        }
        __syncthreads();
    }

    #pragma unroll
    for (int i = 0; i < 4; ++i) {
        const int r = row0 + ty * 4 + i;
        const int c = col0 + tx * 4;
        float4 o;
        o.x = acc[i][0] + bias[c + 0];
        o.y = acc[i][1] + bias[c + 1];
        o.z = acc[i][2] + bias[c + 2];
        o.w = acc[i][3] + bias[c + 3];
        store4(C + (size_t)r * N + c, o);
    }
}

// ---------------------------------------------------------------------------
// Block means: q_repr/k_repr[bh, n, d] = mean_s q/k[b, n*64+s, h*64+d]
// ---------------------------------------------------------------------------
__global__ __launch_bounds__(64) void block_repr_kernel(
    const bf16_t* __restrict__ qkv,
    float* __restrict__ q_repr, float* __restrict__ k_repr)
{
    const int blk = blockIdx.x;        // (b*H+h)*NB + n
    const int n  = blk & 63;
    const int bh = blk >> 6;
    const int h  = bh & 15, b = bh >> 4;
    const int d  = threadIdx.x;
    const bf16_t* base = qkv + (size_t)(b * L_ + n * BS_) * (3 * D_) + h * HD_ + d;
    float sq = 0.f, sk = 0.f;
    for (int s = 0; s < BS_; ++s) {
        sq += b2f(base[(size_t)s * (3 * D_)]);
        sk += b2f(base[(size_t)s * (3 * D_) + D_]);
    }
    q_repr[(size_t)blk * HD_ + d] = sq * (1.0f / BS_);
    k_repr[(size_t)blk * HD_ + d] = sk * (1.0f / BS_);
}

// ---------------------------------------------------------------------------
// Gumbel-Sinkhorn: one wave per (b,h). gumbel is fp32 input.
// ---------------------------------------------------------------------------
__global__ __launch_bounds__(64) void sinkhorn_kernel(
    const float* __restrict__ q_repr, const float* __restrict__ k_repr,
    const float* __restrict__ gumbel, float* __restrict__ P)
{
    __shared__ float qr[64][65];
    __shared__ float kr[64][65];
    __shared__ float la[64][65];
    const int bh = blockIdx.x;
    const int t  = threadIdx.x;

    for (int i = 0; i < 64; ++i) {
        qr[i][t] = q_repr[((size_t)bh * 64 + i) * 64 + t];
        kr[i][t] = k_repr[((size_t)bh * 64 + i) * 64 + t];
    }
    __syncthreads();

    for (int m = 0; m < 64; ++m) {
        float s = 0.f;
        for (int d = 0; d < 64; ++d) s += qr[t][d] * kr[m][d];
        la[t][m] = (s * SCALE_ + gumbel[((size_t)bh * 64 + t) * 64 + m]) * INV_TEMP;
    }
    __syncthreads();

    for (int it = 0; it < 7; ++it) {
        {   // row pass: thread t owns row t (axis=-1)
            float mx = -1e30f;
            for (int m = 0; m < 64; ++m) mx = fmaxf(mx, la[t][m]);
            float sum = 0.f;
            for (int m = 0; m < 64; ++m) sum += expf(la[t][m] - mx);
            const float lse = mx + logf(sum);
            for (int m = 0; m < 64; ++m) la[t][m] -= lse;
        }
        __syncthreads();
        {   // col pass: thread t owns column t (axis=-2)
            float mx = -1e30f;
            for (int m = 0; m < 64; ++m) mx = fmaxf(mx, la[m][t]);
            float sum = 0.f;
            for (int m = 0; m < 64; ++m) sum += expf(la[m][t] - mx);
            const float lse = mx + logf(sum);
            for (int m = 0; m < 64; ++m) la[m][t] -= lse;
        }
        __syncthreads();
    }

    for (int i = 0; i < 64; ++i)
        P[((size_t)bh * 64 + i) * 64 + t] = expf(la[i][t]);
}

// ---------------------------------------------------------------------------
// Soft-sort: k_sorted[bh,n,f] = sum_m P[bh,n,m] * k[bh,m,f]  (same for v).
// ---------------------------------------------------------------------------
__global__ __launch_bounds__(256) void sort_kv_kernel(
    const float* __restrict__ P, const bf16_t* __restrict__ qkv,
    bf16_t* __restrict__ k_sorted, bf16_t* __restrict__ v_sorted)
{
    __shared__ float Pl[NB_ * NB_];   // [n][m]
    const int tid = threadIdx.x;
    const int bh  = blockIdx.y;
    const int h = bh & 15, b = bh >> 4;
    const int f = blockIdx.x * 256 + tid;     // 0..4095
    const int s = f >> 6, d = f & 63;

    for (int i = tid; i < NB_ * NB_; i += 256)
        Pl[i] = P[(size_t)bh * NB_ * NB_ + i];
    __syncthreads();

    const bf16_t* src = qkv + (size_t)(b * L_ + s) * (3 * D_) + h * HD_ + d;
    for (int kv = 0; kv < 2; ++kv) {
        const bf16_t* sp = src + (kv == 0 ? D_ : 2 * D_);
        float bvals[64];
        #pragma unroll
        for (int m = 0; m < 64; ++m)
            bvals[m] = b2f(sp[(size_t)m * BS_ * (3 * D_)]);
        bf16_t* dst = (kv == 0 ? k_sorted : v_sorted)
                      + (size_t)bh * NB_ * BS_ * HD_ + f;
        for (int n = 0; n < 64; ++n) {
            float acc = 0.f;
            #pragma unroll
            for (int m4 = 0; m4 < 16; ++m4) {
                float4 p = *(const float4*)&Pl[n * 64 + m4 * 4];
                acc += p.x * bvals[m4 * 4 + 0] + p.y * bvals[m4 * 4 + 1]
                     + p.z * bvals[m4 * 4 + 2] + p.w * bvals[m4 * 4 + 3];
            }
            dst[(size_t)n * (BS_ * HD_)] = f2b(acc);
        }
    }
}

// ---------------------------------------------------------------------------
// Block attention: per (b,h,n): scores = q @ [k_own; k_next]^T * SCALE,
// softmax rows (last block: only own 64 keys), out = attn @ [v_own; v_next].
// ---------------------------------------------------------------------------
__global__ __launch_bounds__(256) void attn_kernel(
    const bf16_t* __restrict__ qkv, const bf16_t* __restrict__ k_sorted,
    const bf16_t* __restrict__ v_sorted, bf16_t* __restrict__ attn_out)
{
    __shared__ float qs[32 * 64];
    __shared__ float kv[64 * 64];
    __shared__ float sc[32 * 128];
    const int tid = threadIdx.x;
    const int n  = blockIdx.x & 63;
    const int bh = blockIdx.x >> 6;
    const int h = bh & 15, b = bh >> 4;
    const bool last = (n == NB_ - 1);
    const int khn  = last ? 1 : 2;
    const int kLen = last ? 64 : 128;

    const bf16_t* qbase = qkv + (size_t)(b * L_ + n * BS_) * (3 * D_) + h * HD_;
    const size_t nextoff = ((size_t)bh * NB_ + (n + 1)) * (size_t)(BS_ * HD_);

    for (int sh = 0; sh < 2; ++sh) {
        __syncthreads();   // protect qs/kv/sc from previous iteration readers
        // load q half: rows sh*32 .. sh*32+31
        for (int i = tid; i < 512; i += 256) {
            const int s = i >> 4, d4 = (i & 15) * 4;
            *(float4*)&qs[s * 64 + d4] =
                load4(qbase + (size_t)(sh * 32 + s) * (3 * D_) + d4);
        }
        // ---- scores ----
        for (int kh = 0; kh < khn; ++kh) {
            __syncthreads();
            for (int i = tid; i < 1024; i += 256) {
                const int s = i >> 4, d4 = (i & 15) * 4;
                float4 val;
                if (kh == 0)
                    val = load4(qbase + D_ + (size_t)s * (3 * D_) + d4);
                else
                    val = load4(k_sorted + nextoff + s * 64 + d4);
                *(float4*)&kv[s * 64 + d4] = val;
            }
            __syncthreads();
            if (tid < 128) {
                const int s0 = (tid >> 4) * 4;   // 0..28
                const int k0 = (tid & 15) * 4;   // 0..60
                float acc[4][4] = {};
                for (int j = 0; j < 64; ++j) {
                    const int dd = (j + tid) & 63;
                    float a[4], bb[4];
                    #pragma unroll
                    for (int i = 0; i < 4; ++i) a[i]  = qs[(s0 + i) * 64 + dd];
                    #pragma unroll
                    for (int i = 0; i < 4; ++i) bb[i] = kv[(k0 + i) * 64 + dd];
                    #pragma unroll
                    for (int i = 0; i < 4; ++i)
                        #pragma unroll
                        for (int j2 = 0; j2 < 4; ++j2)
                            acc[i][j2] += a[i] * bb[j2];
                }
                #pragma unroll
                for (int i = 0; i < 4; ++i)
                    #pragma unroll
                    for (int j2 = 0; j2 < 4; ++j2)
                        sc[(s0 + i) * 128 + kh * 64 + k0 + j2] = acc[i][j2] * SCALE_;
            }
        }
        __syncthreads();
        // ---- softmax (32 rows of this half) ----
        if (tid < 32) {
            const int r = tid;
            const int mask = kLen - 1;
            float mx = -1e30f;
            for (int j = 0; j < kLen; ++j) {
                const int k = (j + r) & mask;
                mx = fmaxf(mx, sc[r * 128 + k]);
            }
            float sum = 0.f;
            for (int j = 0; j < kLen; ++j) {
                const int k = (j + r) & mask;
                sum += expf(sc[r * 128 + k] - mx);
            }
            const float inv = 1.0f / sum;
            for (int j = 0; j < kLen; ++j) {
                const int k = (j + r) & mask;
                sc[r * 128 + k] = expf(sc[r * 128 + k] - mx) * inv;
            }
        }
        __syncthreads();
        // ---- PV ----
        float pacc[4][4] = {};
        for (int kh = 0; kh < khn; ++kh) {
            for (int i = tid; i < 1024; i += 256) {
                const int s = i >> 4, d4 = (i & 15) * 4;
                float4 val;
                if (kh == 0)
                    val = load4(qbase + 2 * D_ + (size_t)s * (3 * D_) + d4);
                else
                    val = load4(v_sorted + nextoff + s * 64 + d4);
                *(float4*)&kv[s * 64 + d4] = val;
            }
            __syncthreads();
            if (tid < 128) {
                const int s0 = (tid >> 4) * 4;   // 0..28
                const int d0 = (tid & 15) * 4;   // 0..60
                for (int j = 0; j < 64; ++j) {
                    const int kk = (j + tid) & 63;
                    float p[4], v[4];
                    #pragma unroll
                    for (int i = 0; i < 4; ++i) p[i] = sc[(s0 + i) * 128 + kh * 64 + kk];
                    #pragma unroll
                    for (int i = 0; i < 4; ++i) v[i] = kv[kk * 64 + d0 + i];
                    #pragma unroll
                    for (int i = 0; i < 4; ++i)
                        #pragma unroll
                        for (int j2 = 0; j2 < 4; ++j2)
                            pacc[i][j2] += p[i] * v[j2];
                }
            }
            __syncthreads();   // before next kv overwrite / next sh iteration
        }
        // ---- write out ----
        if (tid < 128) {
            const int s0 = (tid >> 4) * 4;
            const int d0 = (tid & 15) * 4;
            #pragma unroll
            for (int i = 0; i < 4; ++i) {
                float4 o = {pacc[i][0], pacc[i][1], pacc[i][2], pacc[i][3]};
                store4(attn_out
                    + (size_t)(b * L_ + n * BS_ + sh * 32 + s0 + i) * D_
                    + h * HD_ + d0, o);
            }
        }
    }
}

// ---------------------------------------------------------------------------
extern "C" void kernel_launch(void* const* d_in, const int* in_sizes, int n_in,
                              void* d_out, int out_size, void* d_ws, size_t ws_size,
                              hipStream_t stream)
{
    const float* x      = (const float*)d_in[0];
    const float* gumbel = (const float*)d_in[1];
    const float* W_qkv  = (const float*)d_in[2];
    const float* b_qkv  = (const float*)d_in[3];
    const float* W_out  = (const float*)d_in[4];
    const float* b_out  = (const float*)d_in[5];
    float* out = (float*)d_out;   // reference output dtype = float32

    // workspace layout (bytes):
    //   qkv    bf16 [B,L,3D]        100,663,296
    //   attn_o bf16 [B,L,D]          33,554,432
    //   ksort  bf16 [BH,NB,BS,HD]    33,554,432
    //   vsort  bf16 [BH,NB,BS,HD]    33,554,432
    //   q_repr f32  [BH,NB,HD]        1,048,576
    //   k_repr f32                    1,048,576
    //   P      f32  [BH,NB,NB]        1,048,576
    const size_t need = 204472320ull;
    if (ws_size < need) {
        fprintf(stderr, "[kernel_launch] ws_size=%zu < need=%zu; in_sizes[0]=%d out_size=%d — aborting launch\n",
                ws_size, need, in_sizes[0], out_size);
        return;
    }

    bf16_t* qkv      = (bf16_t*)d_ws;
    bf16_t* attn_o   = qkv    + (size_t)B_ * L_ * 3 * D_;
    bf16_t* k_sorted = attn_o + (size_t)B_ * L_ * D_;
    bf16_t* v_sorted = k_sorted + (size_t)B_ * L_ * D_;
    float* q_repr    = (float*)(v_sorted + (size_t)B_ * L_ * D_);
    float* k_repr    = q_repr + (size_t)B_ * H_ * NB_ * HD_;
    float* P         = k_repr + (size_t)B_ * H_ * NB_ * HD_;

    // 1. QKV projection: [16384,1024] @ [1024,3072] + bias  (fp32 in, bf16 out)
    gemm_bias_kernel<float, float, bf16_t>
        <<<dim3(3 * D_ / 64, B_ * L_ / 64), dim3(16, 16), 0, stream>>>(
        x, W_qkv, b_qkv, qkv, B_ * L_, 3 * D_, D_);

    // 2. block means
    block_repr_kernel<<<B_ * H_ * NB_, 64, 0, stream>>>(qkv, q_repr, k_repr);

    // 3. Gumbel-Sinkhorn -> P
    sinkhorn_kernel<<<B_ * H_, 64, 0, stream>>>(q_repr, k_repr, gumbel, P);

    // 4. soft-sort K/V blocks
    sort_kv_kernel<<<dim3(16, B_ * H_), 256, 0, stream>>>(P, qkv, k_sorted, v_sorted);

    // 5. block-local attention
    attn_kernel<<<B_ * H_ * NB_, 256, 0, stream>>>(qkv, k_sorted, v_sorted, attn_o);

    // 6. output projection: [16384,1024] @ [1024,1024] + bias  (bf16 x fp32 -> fp32 out)
    gemm_bias_kernel<bf16_t, float, float>
        <<<dim3(D_ / 64, B_ * L_ / 64), dim3(16, 16), 0, stream>>>(
        attn_o, W_out, b_out, out, B_ * L_, D_, D_);
}

// Round 5
// 952.235 us; speedup vs baseline: 2.5294x; 2.5294x over previous
//
#include <hip/hip_runtime.h>
#include <cstdint>
#include <cstddef>
#include <cstdio>

#define B_   4
#define L_   4096
#define D_   1024
#define H_   16
#define BS_  64
#define HD_  64
#define NB_  64
#define SCALE_   0.125f
#define INV_TEMP (1.0f/0.7f)

typedef unsigned short bf16_t;

#ifndef __has_builtin
#define __has_builtin(x) 0
#endif
#if __has_builtin(__builtin_amdgcn_global_load_lds)
#define HAS_GLD 1
#else
#define HAS_GLD 0
#endif

#if HAS_GLD
// LDS dest = wave-uniform base + lane*16 (HW scatter). Global addr per-lane.
// Generic->as(3) via 32-bit truncation (LDS aperture is 2^48-aligned; low 32
// bits of a generic LDS address are the LDS offset — CK-proven pattern).
#define GLD16(gp, lp) __builtin_amdgcn_global_load_lds(                        \
    (__attribute__((address_space(1))) void*)(uintptr_t)(gp),                  \
    (__attribute__((address_space(3))) void*)(unsigned int)(uintptr_t)(lp),    \
    16, 0, 0)
#endif

__device__ __forceinline__ float b2f(bf16_t u) {
    union { unsigned int i; float f; } c; c.i = ((unsigned int)u) << 16; return c.f;
}
__device__ __forceinline__ bf16_t f2b(float f) {
    union { float f; unsigned int i; } c; c.f = f;
    unsigned int r = c.i + 0x7FFFu + ((c.i >> 16) & 1u);   // RNE
    return (bf16_t)(r >> 16);
}

__device__ __forceinline__ float4 load4(const float* p) { return *(const float4*)p; }
__device__ __forceinline__ float4 load4(const bf16_t* p) {
    ushort4 u = *(const ushort4*)p;
    return float4{b2f(u.x), b2f(u.y), b2f(u.z), b2f(u.w)};
}
__device__ __forceinline__ void storeC(float* p, float v)  { *p = v; }
__device__ __forceinline__ void storeC(bf16_t* p, float v) { *p = f2b(v); }

using bf16x8 = __attribute__((ext_vector_type(8))) short;
using f32x4  = __attribute__((ext_vector_type(4))) float;

// ---------------------------------------------------------------------------
// fp32 -> bf16 elementwise (4 elems/thread)
// ---------------------------------------------------------------------------
__global__ __launch_bounds__(256) void f32_to_bf16_kernel(
    const float* __restrict__ src, bf16_t* __restrict__ dst, int n4)
{
    const int i = blockIdx.x * 256 + threadIdx.x;
    if (i < n4) {
        float4 v = *(const float4*)(src + (size_t)i * 4);
        ushort4 o = {f2b(v.x), f2b(v.y), f2b(v.z), f2b(v.w)};
        *(ushort4*)(dst + (size_t)i * 4) = o;
    }
}

// ---------------------------------------------------------------------------
// fp32 [R][C] -> bf16 [C][R] transpose (32x32 LDS tile, block 32x8)
// ---------------------------------------------------------------------------
__global__ __launch_bounds__(256) void transpose_f32_bf16_kernel(
    const float* __restrict__ src, bf16_t* __restrict__ dst, int R, int C)
{
    __shared__ float t[32][33];
    const int c0 = blockIdx.x * 32, r0 = blockIdx.y * 32;
    for (int i = threadIdx.y; i < 32; i += 8)
        t[i][threadIdx.x] = src[(size_t)(r0 + i) * C + c0 + threadIdx.x];
    __syncthreads();
    for (int i = threadIdx.y; i < 32; i += 8)
        dst[(size_t)(c0 + i) * R + r0 + threadIdx.x] = f2b(t[threadIdx.x][i]);
}

// ---------------------------------------------------------------------------
// MFMA bf16 GEMM (m97 structure): C[M,N] = A[M,K] @ Bt[N,K]^T + bias[N]
// 128x128 tile, BK=32, 256 thr = 4 waves (2x2 of 64x64), each wave 4x4 of
// mfma_f32_16x16x32_bf16. global_load_lds width-16 staging (VGPR fallback).
// Verified fragment maps (learn_hip m89/m91/m97):
//   A-frag: A[m=lane&15][k=(lane>>4)*8+j]   B-frag: B^T[n=lane&15][k=...]
//   C/D:    col=lane&15, row=(lane>>4)*4+reg
// ---------------------------------------------------------------------------
template<typename TC>
__global__ __launch_bounds__(256) void mfma_gemm_bt_kernel(
    const bf16_t* __restrict__ A, const bf16_t* __restrict__ Bt,
    const float* __restrict__ bias, TC* __restrict__ C,
    int M, int N, int K)
{
    __shared__ short As_s[128 * 32];   // [m][k] row-major, 8 KB
    __shared__ short Bs_s[128 * 32];   // [n][k] row-major, 8 KB
    const int tid  = threadIdx.x;
    const int lane = tid & 63;
    const int w    = tid >> 6;          // wave 0..3
    const int wm   = w >> 1, wn = w & 1;
    const int m0 = blockIdx.y * 128, n0 = blockIdx.x * 128;

    // staging: wave w covers tile rows 32w..32w+31 of As and Bs.
    // lane l -> row16 = l>>2 within a 16-row issue, k-chunk (l&3)*8 elems.
    const int srow = 32 * w + (lane >> 2);
    const int scol = (lane & 3) * 8;
    const bf16_t* gA = A  + (size_t)(m0 + srow) * K + scol;
    const bf16_t* gB = Bt + (size_t)(n0 + srow) * K + scol;
    short* lAu = &As_s[(32 * w) * 32];   // wave-uniform LDS bases
    short* lBu = &Bs_s[(32 * w) * 32];

    const int ml = lane & 15;
    const int q8 = (lane >> 4) * 8;

    f32x4 acc[4][4];
    #pragma unroll
    for (int i = 0; i < 4; ++i)
        #pragma unroll
        for (int j = 0; j < 4; ++j)
            acc[i][j] = {0.f, 0.f, 0.f, 0.f};

    const int KT = K >> 5;

    auto stage = [&](int kt) {
        const size_t ko = (size_t)kt * 32;
#if HAS_GLD
        GLD16(gA + ko,                lAu);
        GLD16(gA + (size_t)16 * K + ko, lAu + 16 * 32);
        GLD16(gB + ko,                lBu);
        GLD16(gB + (size_t)16 * K + ko, lBu + 16 * 32);
#else
        bf16x8 va0 = *(const bf16x8*)(gA + ko);
        bf16x8 va1 = *(const bf16x8*)(gA + (size_t)16 * K + ko);
        bf16x8 vb0 = *(const bf16x8*)(gB + ko);
        bf16x8 vb1 = *(const bf16x8*)(gB + (size_t)16 * K + ko);
        *(bf16x8*)(lAu + lane * 8)           = va0;
        *(bf16x8*)(lAu + 16 * 32 + lane * 8) = va1;
        *(bf16x8*)(lBu + lane * 8)           = vb0;
        *(bf16x8*)(lBu + 16 * 32 + lane * 8) = vb1;
#endif
    };

    stage(0);
    for (int kt = 0; kt < KT; ++kt) {
        __syncthreads();                      // staged tile visible (drains vmcnt)
        bf16x8 af[4], bfr[4];
        #pragma unroll
        for (int i = 0; i < 4; ++i) {
            af[i]  = *(const bf16x8*)&As_s[(wm * 64 + i * 16 + ml) * 32 + q8];
            bfr[i] = *(const bf16x8*)&Bs_s[(wn * 64 + i * 16 + ml) * 32 + q8];
        }
        #pragma unroll
        for (int i = 0; i < 4; ++i)
            #pragma unroll
            for (int j = 0; j < 4; ++j)
                acc[i][j] = __builtin_amdgcn_mfma_f32_16x16x32_bf16(
                    af[i], bfr[j], acc[i][j], 0, 0, 0);
        __syncthreads();                      // all waves done reading LDS
        if (kt + 1 < KT) stage(kt + 1);
    }

    float bv[4];
    #pragma unroll
    for (int j = 0; j < 4; ++j) bv[j] = bias[n0 + wn * 64 + j * 16 + ml];
    const int r0e = (lane >> 4) * 4;
    #pragma unroll
    for (int i = 0; i < 4; ++i)
        #pragma unroll
        for (int j = 0; j < 4; ++j)
            #pragma unroll
            for (int r = 0; r < 4; ++r) {
                const int row = m0 + wm * 64 + i * 16 + r0e + r;
                const int col = n0 + wn * 64 + j * 16 + ml;
                storeC(&C[(size_t)row * N + col], acc[i][j][r] + bv[j]);
            }
}

// ---------------------------------------------------------------------------
// Block means: q_repr/k_repr[bh, n, d] = mean_s q/k[b, n*64+s, h*64+d]
// ---------------------------------------------------------------------------
__global__ __launch_bounds__(64) void block_repr_kernel(
    const bf16_t* __restrict__ qkv,
    float* __restrict__ q_repr, float* __restrict__ k_repr)
{
    const int blk = blockIdx.x;        // (b*H+h)*NB + n
    const int n  = blk & 63;
    const int bh = blk >> 6;
    const int h  = bh & 15, b = bh >> 4;
    const int d  = threadIdx.x;
    const bf16_t* base = qkv + (size_t)(b * L_ + n * BS_) * (3 * D_) + h * HD_ + d;
    float sq = 0.f, sk = 0.f;
    for (int s = 0; s < BS_; ++s) {
        sq += b2f(base[(size_t)s * (3 * D_)]);
        sk += b2f(base[(size_t)s * (3 * D_) + D_]);
    }
    q_repr[(size_t)blk * HD_ + d] = sq * (1.0f / BS_);
    k_repr[(size_t)blk * HD_ + d] = sk * (1.0f / BS_);
}

// ---------------------------------------------------------------------------
// Gumbel-Sinkhorn: one wave per (b,h). gumbel is fp32 input.
// ---------------------------------------------------------------------------
__global__ __launch_bounds__(64) void sinkhorn_kernel(
    const float* __restrict__ q_repr, const float* __restrict__ k_repr,
    const float* __restrict__ gumbel, float* __restrict__ P)
{
    __shared__ float qr[64][65];
    __shared__ float kr[64][65];
    __shared__ float la[64][65];
    const int bh = blockIdx.x;
    const int t  = threadIdx.x;

    for (int i = 0; i < 64; ++i) {
        qr[i][t] = q_repr[((size_t)bh * 64 + i) * 64 + t];
        kr[i][t] = k_repr[((size_t)bh * 64 + i) * 64 + t];
    }
    __syncthreads();

    for (int m = 0; m < 64; ++m) {
        float s = 0.f;
        for (int d = 0; d < 64; ++d) s += qr[t][d] * kr[m][d];
        la[t][m] = (s * SCALE_ + gumbel[((size_t)bh * 64 + t) * 64 + m]) * INV_TEMP;
    }
    __syncthreads();

    for (int it = 0; it < 7; ++it) {
        {   // row pass (axis=-1)
            float mx = -1e30f;
            for (int m = 0; m < 64; ++m) mx = fmaxf(mx, la[t][m]);
            float sum = 0.f;
            for (int m = 0; m < 64; ++m) sum += expf(la[t][m] - mx);
            const float lse = mx + logf(sum);
            for (int m = 0; m < 64; ++m) la[t][m] -= lse;
        }
        __syncthreads();
        {   // col pass (axis=-2)
            float mx = -1e30f;
            for (int m = 0; m < 64; ++m) mx = fmaxf(mx, la[m][t]);
            float sum = 0.f;
            for (int m = 0; m < 64; ++m) sum += expf(la[m][t] - mx);
            const float lse = mx + logf(sum);
            for (int m = 0; m < 64; ++m) la[m][t] -= lse;
        }
        __syncthreads();
    }

    for (int i = 0; i < 64; ++i)
        P[((size_t)bh * 64 + i) * 64 + t] = expf(la[i][t]);
}

// ---------------------------------------------------------------------------
// Soft-sort: k_sorted[bh,n,f] = sum_m P[bh,n,m] * k[bh,m,f]  (same for v).
// ---------------------------------------------------------------------------
__global__ __launch_bounds__(256) void sort_kv_kernel(
    const float* __restrict__ P, const bf16_t* __restrict__ qkv,
    bf16_t* __restrict__ k_sorted, bf16_t* __restrict__ v_sorted)
{
    __shared__ float Pl[NB_ * NB_];   // [n][m]
    const int tid = threadIdx.x;
    const int bh  = blockIdx.y;
    const int h = bh & 15, b = bh >> 4;
    const int f = blockIdx.x * 256 + tid;     // 0..4095
    const int s = f >> 6, d = f & 63;

    for (int i = tid; i < NB_ * NB_; i += 256)
        Pl[i] = P[(size_t)bh * NB_ * NB_ + i];
    __syncthreads();

    const bf16_t* src = qkv + (size_t)(b * L_ + s) * (3 * D_) + h * HD_ + d;
    for (int kv = 0; kv < 2; ++kv) {
        const bf16_t* sp = src + (kv == 0 ? D_ : 2 * D_);
        float bvals[64];
        #pragma unroll
        for (int m = 0; m < 64; ++m)
            bvals[m] = b2f(sp[(size_t)m * BS_ * (3 * D_)]);
        bf16_t* dst = (kv == 0 ? k_sorted : v_sorted)
                      + (size_t)bh * NB_ * BS_ * HD_ + f;
        for (int n = 0; n < 64; ++n) {
            float acc = 0.f;
            #pragma unroll
            for (int m4 = 0; m4 < 16; ++m4) {
                float4 p = *(const float4*)&Pl[n * 64 + m4 * 4];
                acc += p.x * bvals[m4 * 4 + 0] + p.y * bvals[m4 * 4 + 1]
                     + p.z * bvals[m4 * 4 + 2] + p.w * bvals[m4 * 4 + 3];
            }
            dst[(size_t)n * (BS_ * HD_)] = f2b(acc);
        }
    }
}

// ---------------------------------------------------------------------------
// Block attention: per (b,h,n): scores = q @ [k_own; k_next]^T * SCALE,
// softmax rows (last block: only own 64 keys), out = attn @ [v_own; v_next].
// ---------------------------------------------------------------------------
__global__ __launch_bounds__(256) void attn_kernel(
    const bf16_t* __restrict__ qkv, const bf16_t* __restrict__ k_sorted,
    const bf16_t* __restrict__ v_sorted, bf16_t* __restrict__ attn_out)
{
    __shared__ float qs[32 * 64];
    __shared__ float kv[64 * 64];
    __shared__ float sc[32 * 128];
    const int tid = threadIdx.x;
    const int n  = blockIdx.x & 63;
    const int bh = blockIdx.x >> 6;
    const int h = bh & 15, b = bh >> 4;
    const bool last = (n == NB_ - 1);
    const int khn  = last ? 1 : 2;
    const int kLen = last ? 64 : 128;

    const bf16_t* qbase = qkv + (size_t)(b * L_ + n * BS_) * (3 * D_) + h * HD_;
    const size_t nextoff = ((size_t)bh * NB_ + (n + 1)) * (size_t)(BS_ * HD_);

    for (int sh = 0; sh < 2; ++sh) {
        __syncthreads();
        for (int i = tid; i < 512; i += 256) {
            const int s = i >> 4, d4 = (i & 15) * 4;
            *(float4*)&qs[s * 64 + d4] =
                load4(qbase + (size_t)(sh * 32 + s) * (3 * D_) + d4);
        }
        // ---- scores ----
        for (int kh = 0; kh < khn; ++kh) {
            __syncthreads();
            for (int i = tid; i < 1024; i += 256) {
                const int s = i >> 4, d4 = (i & 15) * 4;
                float4 val;
                if (kh == 0)
                    val = load4(qbase + D_ + (size_t)s * (3 * D_) + d4);
                else
                    val = load4(k_sorted + nextoff + s * 64 + d4);
                *(float4*)&kv[s * 64 + d4] = val;
            }
            __syncthreads();
            if (tid < 128) {
                const int s0 = (tid >> 4) * 4;
                const int k0 = (tid & 15) * 4;
                float acc[4][4] = {};
                for (int j = 0; j < 64; ++j) {
                    const int dd = (j + tid) & 63;
                    float a[4], bb[4];
                    #pragma unroll
                    for (int i = 0; i < 4; ++i) a[i]  = qs[(s0 + i) * 64 + dd];
                    #pragma unroll
                    for (int i = 0; i < 4; ++i) bb[i] = kv[(k0 + i) * 64 + dd];
                    #pragma unroll
                    for (int i = 0; i < 4; ++i)
                        #pragma unroll
                        for (int j2 = 0; j2 < 4; ++j2)
                            acc[i][j2] += a[i] * bb[j2];
                }
                #pragma unroll
                for (int i = 0; i < 4; ++i)
                    #pragma unroll
                    for (int j2 = 0; j2 < 4; ++j2)
                        sc[(s0 + i) * 128 + kh * 64 + k0 + j2] = acc[i][j2] * SCALE_;
            }
        }
        __syncthreads();
        // ---- softmax ----
        if (tid < 32) {
            const int r = tid;
            const int mask = kLen - 1;
            float mx = -1e30f;
            for (int j = 0; j < kLen; ++j) {
                const int k = (j + r) & mask;
                mx = fmaxf(mx, sc[r * 128 + k]);
            }
            float sum = 0.f;
            for (int j = 0; j < kLen; ++j) {
                const int k = (j + r) & mask;
                sum += expf(sc[r * 128 + k] - mx);
            }
            const float inv = 1.0f / sum;
            for (int j = 0; j < kLen; ++j) {
                const int k = (j + r) & mask;
                sc[r * 128 + k] = expf(sc[r * 128 + k] - mx) * inv;
            }
        }
        __syncthreads();
        // ---- PV ----
        float pacc[4][4] = {};
        for (int kh = 0; kh < khn; ++kh) {
            for (int i = tid; i < 1024; i += 256) {
                const int s = i >> 4, d4 = (i & 15) * 4;
                float4 val;
                if (kh == 0)
                    val = load4(qbase + 2 * D_ + (size_t)s * (3 * D_) + d4);
                else
                    val = load4(v_sorted + nextoff + s * 64 + d4);
                *(float4*)&kv[s * 64 + d4] = val;
            }
            __syncthreads();
            if (tid < 128) {
                const int s0 = (tid >> 4) * 4;
                const int d0 = (tid & 15) * 4;
                for (int j = 0; j < 64; ++j) {
                    const int kk = (j + tid) & 63;
                    float p[4], v[4];
                    #pragma unroll
                    for (int i = 0; i < 4; ++i) p[i] = sc[(s0 + i) * 128 + kh * 64 + kk];
                    #pragma unroll
                    for (int i = 0; i < 4; ++i) v[i] = kv[kk * 64 + d0 + i];
                    #pragma unroll
                    for (int i = 0; i < 4; ++i)
                        #pragma unroll
                        for (int j2 = 0; j2 < 4; ++j2)
                            pacc[i][j2] += p[i] * v[j2];
                }
            }
            __syncthreads();
        }
        // ---- write out ----
        if (tid < 128) {
            const int s0 = (tid >> 4) * 4;
            const int d0 = (tid & 15) * 4;
            #pragma unroll
            for (int i = 0; i < 4; ++i) {
                ushort4 o = {f2b(pacc[i][0]), f2b(pacc[i][1]),
                             f2b(pacc[i][2]), f2b(pacc[i][3])};
                *(ushort4*)(attn_out
                    + (size_t)(b * L_ + n * BS_ + sh * 32 + s0 + i) * D_
                    + h * HD_ + d0) = o;
            }
        }
    }
}

// ---------------------------------------------------------------------------
extern "C" void kernel_launch(void* const* d_in, const int* in_sizes, int n_in,
                              void* d_out, int out_size, void* d_ws, size_t ws_size,
                              hipStream_t stream)
{
    const float* x      = (const float*)d_in[0];
    const float* gumbel = (const float*)d_in[1];
    const float* W_qkv  = (const float*)d_in[2];
    const float* b_qkv  = (const float*)d_in[3];
    const float* W_out  = (const float*)d_in[4];
    const float* b_out  = (const float*)d_in[5];
    float* out = (float*)d_out;   // fp32 output (verified round 4)

    // ws layout (unchanged, known-good 204,472,320 B):
    //   qkv bf16 | attn_o bf16 | ksort bf16 | vsort bf16 | q_repr f32 |
    //   k_repr f32 | P f32
    const size_t need = 204472320ull;
    if (ws_size < need) {
        fprintf(stderr, "[kernel_launch] ws_size=%zu < need=%zu — aborting launch\n",
                ws_size, need);
        return;
    }

    bf16_t* qkv      = (bf16_t*)d_ws;
    bf16_t* attn_o   = qkv    + (size_t)B_ * L_ * 3 * D_;
    bf16_t* k_sorted = attn_o + (size_t)B_ * L_ * D_;
    bf16_t* v_sorted = k_sorted + (size_t)B_ * L_ * D_;
    float* q_repr    = (float*)(v_sorted + (size_t)B_ * L_ * D_);
    float* k_repr    = q_repr + (size_t)B_ * H_ * NB_ * HD_;
    float* P         = k_repr + (size_t)B_ * H_ * NB_ * HD_;

    // d_out (64 MB) doubles as scratch until the final GEMM overwrites it:
    //   x_bf16  [16384,1024] bf16  (32 MB)   dead after GEMM1
    //   Wqkv_t  [3072,1024]  bf16  ( 6 MB)   dead after GEMM1
    bf16_t* x_bf   = (bf16_t*)d_out;
    bf16_t* Wqkv_t = x_bf + (size_t)B_ * L_ * D_;
    // Wout_t (2 MB) overwrites q_repr+k_repr (dead after sinkhorn)
    bf16_t* Wout_t = (bf16_t*)q_repr;

    // 0a. x -> bf16
    f32_to_bf16_kernel<<<(B_ * L_ * D_ / 4 + 255) / 256, 256, 0, stream>>>(
        x, x_bf, B_ * L_ * D_ / 4);
    // 0b. W_qkv [1024,3072] -> Wqkv_t bf16 [3072,1024]
    transpose_f32_bf16_kernel<<<dim3(3 * D_ / 32, D_ / 32), dim3(32, 8), 0, stream>>>(
        W_qkv, Wqkv_t, D_, 3 * D_);

    // 1. QKV projection (MFMA bf16): [16384,1024] @ [1024,3072] + bias -> bf16
    mfma_gemm_bt_kernel<bf16_t>
        <<<dim3(3 * D_ / 128, B_ * L_ / 128), 256, 0, stream>>>(
        x_bf, Wqkv_t, b_qkv, qkv, B_ * L_, 3 * D_, D_);

    // 2. block means
    block_repr_kernel<<<B_ * H_ * NB_, 64, 0, stream>>>(qkv, q_repr, k_repr);

    // 3. Gumbel-Sinkhorn -> P
    sinkhorn_kernel<<<B_ * H_, 64, 0, stream>>>(q_repr, k_repr, gumbel, P);

    // 4. soft-sort K/V blocks
    sort_kv_kernel<<<dim3(16, B_ * H_), 256, 0, stream>>>(P, qkv, k_sorted, v_sorted);

    // 5. block-local attention
    attn_kernel<<<B_ * H_ * NB_, 256, 0, stream>>>(qkv, k_sorted, v_sorted, attn_o);

    // 5b. W_out [1024,1024] -> Wout_t bf16 [1024,1024] (into dead q_repr/k_repr)
    transpose_f32_bf16_kernel<<<dim3(D_ / 32, D_ / 32), dim3(32, 8), 0, stream>>>(
        W_out, Wout_t, D_, D_);

    // 6. output projection (MFMA bf16): [16384,1024] @ [1024,1024] + bias -> fp32
    mfma_gemm_bt_kernel<float>
        <<<dim3(D_ / 128, B_ * L_ / 128), 256, 0, stream>>>(
        attn_o, Wout_t, b_out, out, B_ * L_, D_, D_);
}

// Round 6
// 627.666 us; speedup vs baseline: 3.8374x; 1.5171x over previous
//
#include <hip/hip_runtime.h>
#include <cstdint>
#include <cstddef>
#include <cstdio>

#define B_   4
#define L_   4096
#define D_   1024
#define H_   16
#define BS_  64
#define HD_  64
#define NB_  64
#define SCALE_   0.125f
#define INV_TEMP (1.0f/0.7f)

typedef unsigned short bf16_t;

#ifndef __has_builtin
#define __has_builtin(x) 0
#endif
#if __has_builtin(__builtin_amdgcn_global_load_lds)
#define HAS_GLD 1
#else
#define HAS_GLD 0
#endif

#if HAS_GLD
#define GLD16(gp, lp) __builtin_amdgcn_global_load_lds(                        \
    (__attribute__((address_space(1))) void*)(uintptr_t)(gp),                  \
    (__attribute__((address_space(3))) void*)(unsigned int)(uintptr_t)(lp),    \
    16, 0, 0)
#endif

__device__ __forceinline__ float b2f(bf16_t u) {
    union { unsigned int i; float f; } c; c.i = ((unsigned int)u) << 16; return c.f;
}
__device__ __forceinline__ bf16_t f2b(float f) {
    union { float f; unsigned int i; } c; c.f = f;
    unsigned int r = c.i + 0x7FFFu + ((c.i >> 16) & 1u);   // RNE
    return (bf16_t)(r >> 16);
}

__device__ __forceinline__ float4 load4(const float* p) { return *(const float4*)p; }
__device__ __forceinline__ float4 load4(const bf16_t* p) {
    ushort4 u = *(const ushort4*)p;
    return float4{b2f(u.x), b2f(u.y), b2f(u.z), b2f(u.w)};
}
__device__ __forceinline__ void storeC(float* p, float v)  { *p = v; }
__device__ __forceinline__ void storeC(bf16_t* p, float v) { *p = f2b(v); }

using bf16x8 = __attribute__((ext_vector_type(8))) short;
using f32x4  = __attribute__((ext_vector_type(4))) float;

// ---------------------------------------------------------------------------
// fp32 -> bf16 elementwise (4 elems/thread)
// ---------------------------------------------------------------------------
__global__ __launch_bounds__(256) void f32_to_bf16_kernel(
    const float* __restrict__ src, bf16_t* __restrict__ dst, int n4)
{
    const int i = blockIdx.x * 256 + threadIdx.x;
    if (i < n4) {
        float4 v = *(const float4*)(src + (size_t)i * 4);
        ushort4 o = {f2b(v.x), f2b(v.y), f2b(v.z), f2b(v.w)};
        *(ushort4*)(dst + (size_t)i * 4) = o;
    }
}

// ---------------------------------------------------------------------------
// fp32 [R][C] -> bf16 [C][R] transpose (32x32 LDS tile, block 32x8)
// ---------------------------------------------------------------------------
__global__ __launch_bounds__(256) void transpose_f32_bf16_kernel(
    const float* __restrict__ src, bf16_t* __restrict__ dst, int R, int C)
{
    __shared__ float t[32][33];
    const int c0 = blockIdx.x * 32, r0 = blockIdx.y * 32;
    for (int i = threadIdx.y; i < 32; i += 8)
        t[i][threadIdx.x] = src[(size_t)(r0 + i) * C + c0 + threadIdx.x];
    __syncthreads();
    for (int i = threadIdx.y; i < 32; i += 8)
        dst[(size_t)(c0 + i) * R + r0 + threadIdx.x] = f2b(t[threadIdx.x][i]);
}

// ---------------------------------------------------------------------------
// MFMA bf16 GEMM (m97 structure): C[M,N] = A[M,K] @ Bt[N,K]^T + bias[N]
// (verified round 5)
// ---------------------------------------------------------------------------
template<typename TC>
__global__ __launch_bounds__(256) void mfma_gemm_bt_kernel(
    const bf16_t* __restrict__ A, const bf16_t* __restrict__ Bt,
    const float* __restrict__ bias, TC* __restrict__ C,
    int M, int N, int K)
{
    __shared__ short As_s[128 * 32];
    __shared__ short Bs_s[128 * 32];
    const int tid  = threadIdx.x;
    const int lane = tid & 63;
    const int w    = tid >> 6;
    const int wm   = w >> 1, wn = w & 1;
    const int m0 = blockIdx.y * 128, n0 = blockIdx.x * 128;

    const int srow = 32 * w + (lane >> 2);
    const int scol = (lane & 3) * 8;
    const bf16_t* gA = A  + (size_t)(m0 + srow) * K + scol;
    const bf16_t* gB = Bt + (size_t)(n0 + srow) * K + scol;
    short* lAu = &As_s[(32 * w) * 32];
    short* lBu = &Bs_s[(32 * w) * 32];

    const int ml = lane & 15;
    const int q8 = (lane >> 4) * 8;

    f32x4 acc[4][4];
    #pragma unroll
    for (int i = 0; i < 4; ++i)
        #pragma unroll
        for (int j = 0; j < 4; ++j)
            acc[i][j] = {0.f, 0.f, 0.f, 0.f};

    const int KT = K >> 5;

    auto stage = [&](int kt) {
        const size_t ko = (size_t)kt * 32;
#if HAS_GLD
        GLD16(gA + ko,                lAu);
        GLD16(gA + (size_t)16 * K + ko, lAu + 16 * 32);
        GLD16(gB + ko,                lBu);
        GLD16(gB + (size_t)16 * K + ko, lBu + 16 * 32);
#else
        bf16x8 va0 = *(const bf16x8*)(gA + ko);
        bf16x8 va1 = *(const bf16x8*)(gA + (size_t)16 * K + ko);
        bf16x8 vb0 = *(const bf16x8*)(gB + ko);
        bf16x8 vb1 = *(const bf16x8*)(gB + (size_t)16 * K + ko);
        *(bf16x8*)(lAu + lane * 8)           = va0;
        *(bf16x8*)(lAu + 16 * 32 + lane * 8) = va1;
        *(bf16x8*)(lBu + lane * 8)           = vb0;
        *(bf16x8*)(lBu + 16 * 32 + lane * 8) = vb1;
#endif
    };

    stage(0);
    for (int kt = 0; kt < KT; ++kt) {
        __syncthreads();
        bf16x8 af[4], bfr[4];
        #pragma unroll
        for (int i = 0; i < 4; ++i) {
            af[i]  = *(const bf16x8*)&As_s[(wm * 64 + i * 16 + ml) * 32 + q8];
            bfr[i] = *(const bf16x8*)&Bs_s[(wn * 64 + i * 16 + ml) * 32 + q8];
        }
        #pragma unroll
        for (int i = 0; i < 4; ++i)
            #pragma unroll
            for (int j = 0; j < 4; ++j)
                acc[i][j] = __builtin_amdgcn_mfma_f32_16x16x32_bf16(
                    af[i], bfr[j], acc[i][j], 0, 0, 0);
        __syncthreads();
        if (kt + 1 < KT) stage(kt + 1);
    }

    float bv[4];
    #pragma unroll
    for (int j = 0; j < 4; ++j) bv[j] = bias[n0 + wn * 64 + j * 16 + ml];
    const int r0e = (lane >> 4) * 4;
    #pragma unroll
    for (int i = 0; i < 4; ++i)
        #pragma unroll
        for (int j = 0; j < 4; ++j)
            #pragma unroll
            for (int r = 0; r < 4; ++r) {
                const int row = m0 + wm * 64 + i * 16 + r0e + r;
                const int col = n0 + wn * 64 + j * 16 + ml;
                storeC(&C[(size_t)row * N + col], acc[i][j][r] + bv[j]);
            }
}

// ---------------------------------------------------------------------------
// Block means
// ---------------------------------------------------------------------------
__global__ __launch_bounds__(64) void block_repr_kernel(
    const bf16_t* __restrict__ qkv,
    float* __restrict__ q_repr, float* __restrict__ k_repr)
{
    const int blk = blockIdx.x;
    const int n  = blk & 63;
    const int bh = blk >> 6;
    const int h  = bh & 15, b = bh >> 4;
    const int d  = threadIdx.x;
    const bf16_t* base = qkv + (size_t)(b * L_ + n * BS_) * (3 * D_) + h * HD_ + d;
    float sq = 0.f, sk = 0.f;
    for (int s = 0; s < BS_; ++s) {
        sq += b2f(base[(size_t)s * (3 * D_)]);
        sk += b2f(base[(size_t)s * (3 * D_) + D_]);
    }
    q_repr[(size_t)blk * HD_ + d] = sq * (1.0f / BS_);
    k_repr[(size_t)blk * HD_ + d] = sk * (1.0f / BS_);
}

// ---------------------------------------------------------------------------
// Gumbel-Sinkhorn
// ---------------------------------------------------------------------------
__global__ __launch_bounds__(64) void sinkhorn_kernel(
    const float* __restrict__ q_repr, const float* __restrict__ k_repr,
    const float* __restrict__ gumbel, float* __restrict__ P)
{
    __shared__ float qr[64][65];
    __shared__ float kr[64][65];
    __shared__ float la[64][65];
    const int bh = blockIdx.x;
    const int t  = threadIdx.x;

    for (int i = 0; i < 64; ++i) {
        qr[i][t] = q_repr[((size_t)bh * 64 + i) * 64 + t];
        kr[i][t] = k_repr[((size_t)bh * 64 + i) * 64 + t];
    }
    __syncthreads();

    for (int m = 0; m < 64; ++m) {
        float s = 0.f;
        for (int d = 0; d < 64; ++d) s += qr[t][d] * kr[m][d];
        la[t][m] = (s * SCALE_ + gumbel[((size_t)bh * 64 + t) * 64 + m]) * INV_TEMP;
    }
    __syncthreads();

    for (int it = 0; it < 7; ++it) {
        {
            float mx = -1e30f;
            for (int m = 0; m < 64; ++m) mx = fmaxf(mx, la[t][m]);
            float sum = 0.f;
            for (int m = 0; m < 64; ++m) sum += expf(la[t][m] - mx);
            const float lse = mx + logf(sum);
            for (int m = 0; m < 64; ++m) la[t][m] -= lse;
        }
        __syncthreads();
        {
            float mx = -1e30f;
            for (int m = 0; m < 64; ++m) mx = fmaxf(mx, la[m][t]);
            float sum = 0.f;
            for (int m = 0; m < 64; ++m) sum += expf(la[m][t] - mx);
            const float lse = mx + logf(sum);
            for (int m = 0; m < 64; ++m) la[m][t] -= lse;
        }
        __syncthreads();
    }

    for (int i = 0; i < 64; ++i)
        P[((size_t)bh * 64 + i) * 64 + t] = expf(la[i][t]);
}

// ---------------------------------------------------------------------------
// Soft-sort
// ---------------------------------------------------------------------------
__global__ __launch_bounds__(256) void sort_kv_kernel(
    const float* __restrict__ P, const bf16_t* __restrict__ qkv,
    bf16_t* __restrict__ k_sorted, bf16_t* __restrict__ v_sorted)
{
    __shared__ float Pl[NB_ * NB_];
    const int tid = threadIdx.x;
    const int bh  = blockIdx.y;
    const int h = bh & 15, b = bh >> 4;
    const int f = blockIdx.x * 256 + tid;
    const int s = f >> 6, d = f & 63;

    for (int i = tid; i < NB_ * NB_; i += 256)
        Pl[i] = P[(size_t)bh * NB_ * NB_ + i];
    __syncthreads();

    const bf16_t* src = qkv + (size_t)(b * L_ + s) * (3 * D_) + h * HD_ + d;
    for (int kv = 0; kv < 2; ++kv) {
        const bf16_t* sp = src + (kv == 0 ? D_ : 2 * D_);
        float bvals[64];
        #pragma unroll
        for (int m = 0; m < 64; ++m)
            bvals[m] = b2f(sp[(size_t)m * BS_ * (3 * D_)]);
        bf16_t* dst = (kv == 0 ? k_sorted : v_sorted)
                      + (size_t)bh * NB_ * BS_ * HD_ + f;
        for (int n = 0; n < 64; ++n) {
            float acc = 0.f;
            #pragma unroll
            for (int m4 = 0; m4 < 16; ++m4) {
                float4 p = *(const float4*)&Pl[n * 64 + m4 * 4];
                acc += p.x * bvals[m4 * 4 + 0] + p.y * bvals[m4 * 4 + 1]
                     + p.z * bvals[m4 * 4 + 2] + p.w * bvals[m4 * 4 + 3];
            }
            dst[(size_t)n * (BS_ * HD_)] = f2b(acc);
        }
    }
}

// ---------------------------------------------------------------------------
// MFMA block attention: one wg (4 waves) per (b,h,n); wave w owns q-rows
// w*16..w*16+15. QK^T via mfma (K from LDS Ks[kidx][d], pad 72 to kill the
// stride-64 16-way bank conflict), softmax in registers (shfl_xor over the
// quad), P -> LDS (bf16, A-frag layout), PV via mfma with V staged
// transposed (Vt[d][kidx], pad 136). Last block: col-tiles 4..7 masked by
// construction. Fragment maps per m89/m91/m97 (HW-verified).
// ---------------------------------------------------------------------------
__global__ __launch_bounds__(256) void attn_mfma_kernel(
    const bf16_t* __restrict__ qkv, const bf16_t* __restrict__ k_sorted,
    const bf16_t* __restrict__ v_sorted, bf16_t* __restrict__ attn_out)
{
    constexpr int KS = 72, VS = 136, PS = 136;
    __shared__ short Ks[128 * KS];    // [kidx][d]   18.0 KB
    __shared__ short Vt[64 * VS];     // [d][kidx]   17.0 KB
    __shared__ short Psh[64 * PS];    // [q][kidx]   17.0 KB
    const int tid = threadIdx.x, lane = tid & 63, w = tid >> 6;
    const int n  = blockIdx.x & 63;
    const int bh = blockIdx.x >> 6;
    const int h = bh & 15, b = bh >> 4;
    const bool last = (n == NB_ - 1);

    const bf16_t* qb = qkv + (size_t)(b * L_ + n * BS_) * (3 * D_) + h * HD_;
    const bf16_t* kb = qb + D_;
    const bf16_t* vb = qb + 2 * D_;
    const size_t nextoff = ((size_t)bh * NB_ + (n + 1)) * (size_t)(BS_ * HD_);
    const bf16_t* kn = k_sorted + nextoff;
    const bf16_t* vn = v_sorted + nextoff;

    // ---- stage K rows 0..127 into Ks[kidx][d] ----
    {
        const int col8 = (tid & 7) * 8, r0 = tid >> 3;       // r0: 0..31
        const int jjmax = last ? 2 : 4;
        for (int jj = 0; jj < jjmax; ++jj) {
            const int row = jj * 32 + r0;
            const bf16_t* src = (row < 64)
                ? kb + (size_t)row * (3 * D_) + col8
                : kn + (size_t)(row - 64) * HD_ + col8;
            *(bf16x8*)&Ks[row * KS + col8] = *(const bf16x8*)src;
        }
    }
    // ---- stage V transposed into Vt[d][kidx] ----
    {
        const int halves = last ? 1 : 2;
        for (int half = 0; half < halves; ++half) {
            for (int jj = 0; jj < 4; ++jj) {
                const int d0 = jj * 16 + w * 4;
                const bf16_t* src = (half == 0)
                    ? vb + (size_t)lane * (3 * D_) + d0
                    : vn + (size_t)lane * HD_ + d0;
                ushort4 u = *(const ushort4*)src;
                const int kcol = half * 64 + lane;
                Vt[(d0 + 0) * VS + kcol] = u.x;
                Vt[(d0 + 1) * VS + kcol] = u.y;
                Vt[(d0 + 2) * VS + kcol] = u.z;
                Vt[(d0 + 3) * VS + kcol] = u.w;
            }
        }
    }

    const int ml = lane & 15, quad = lane >> 4, q8 = quad * 8;
    const int m0 = w * 16;

    // A-frags (Q) straight from global: A[m=ml][k=kt*32+q8+j]
    bf16x8 af0 = *(const bf16x8*)(qb + (size_t)(m0 + ml) * (3 * D_) + q8);
    bf16x8 af1 = *(const bf16x8*)(qb + (size_t)(m0 + ml) * (3 * D_) + 32 + q8);

    __syncthreads();

    // ---- S = Q @ K^T (per wave: 16 q-rows x 128 k-cols) ----
    const int ntile = last ? 4 : 8;
    f32x4 st[8];
    #pragma unroll
    for (int t = 0; t < 8; ++t) st[t] = {0.f, 0.f, 0.f, 0.f};
    for (int t = 0; t < ntile; ++t) {
        bf16x8 b0 = *(const bf16x8*)&Ks[(t * 16 + ml) * KS + q8];
        bf16x8 b1 = *(const bf16x8*)&Ks[(t * 16 + ml) * KS + 32 + q8];
        st[t] = __builtin_amdgcn_mfma_f32_16x16x32_bf16(af0, b0, st[t], 0, 0, 0);
        st[t] = __builtin_amdgcn_mfma_f32_16x16x32_bf16(af1, b1, st[t], 0, 0, 0);
    }

    // ---- softmax over each row (C-layout: row=quad*4+reg, col=ml+16t) ----
    #pragma unroll
    for (int reg = 0; reg < 4; ++reg) {
        float mx = -1e30f;
        for (int t = 0; t < ntile; ++t) mx = fmaxf(mx, st[t][reg] * SCALE_);
        #pragma unroll
        for (int xm = 1; xm <= 8; xm <<= 1)
            mx = fmaxf(mx, __shfl_xor(mx, xm, 64));
        float e[8];
        float sum = 0.f;
        for (int t = 0; t < ntile; ++t) {
            e[t] = __expf(st[t][reg] * SCALE_ - mx);
            sum += e[t];
        }
        #pragma unroll
        for (int xm = 1; xm <= 8; xm <<= 1)
            sum += __shfl_xor(sum, xm, 64);
        const float inv = 1.0f / sum;
        const int qrow = m0 + quad * 4 + reg;
        for (int t = 0; t < ntile; ++t)
            Psh[qrow * PS + t * 16 + ml] = f2b(e[t] * inv);
    }

    __syncthreads();

    // ---- O = P @ V  (A=Psh[q][k], B=Vt[d][k]) ----
    const int ktv = last ? 2 : 4;
    f32x4 oacc[4];
    #pragma unroll
    for (int t = 0; t < 4; ++t) oacc[t] = {0.f, 0.f, 0.f, 0.f};
    for (int kt = 0; kt < ktv; ++kt) {
        bf16x8 pa = *(const bf16x8*)&Psh[(m0 + ml) * PS + kt * 32 + q8];
        #pragma unroll
        for (int t = 0; t < 4; ++t) {
            bf16x8 vf = *(const bf16x8*)&Vt[(t * 16 + ml) * VS + kt * 32 + q8];
            oacc[t] = __builtin_amdgcn_mfma_f32_16x16x32_bf16(pa, vf, oacc[t], 0, 0, 0);
        }
    }

    // ---- store O (C-layout: row=quad*4+reg -> q, col=ml+16t -> d) ----
    bf16_t* ob = attn_out + (size_t)(b * L_ + n * BS_) * D_ + h * HD_;
    #pragma unroll
    for (int t = 0; t < 4; ++t)
        #pragma unroll
        for (int reg = 0; reg < 4; ++reg) {
            const int qrow = m0 + quad * 4 + reg;
            ob[(size_t)qrow * D_ + t * 16 + ml] = f2b(oacc[t][reg]);
        }
}

// ---------------------------------------------------------------------------
extern "C" void kernel_launch(void* const* d_in, const int* in_sizes, int n_in,
                              void* d_out, int out_size, void* d_ws, size_t ws_size,
                              hipStream_t stream)
{
    const float* x      = (const float*)d_in[0];
    const float* gumbel = (const float*)d_in[1];
    const float* W_qkv  = (const float*)d_in[2];
    const float* b_qkv  = (const float*)d_in[3];
    const float* W_out  = (const float*)d_in[4];
    const float* b_out  = (const float*)d_in[5];
    float* out = (float*)d_out;

    const size_t need = 204472320ull;
    if (ws_size < need) {
        fprintf(stderr, "[kernel_launch] ws_size=%zu < need=%zu — aborting launch\n",
                ws_size, need);
        return;
    }

    bf16_t* qkv      = (bf16_t*)d_ws;
    bf16_t* attn_o   = qkv    + (size_t)B_ * L_ * 3 * D_;
    bf16_t* k_sorted = attn_o + (size_t)B_ * L_ * D_;
    bf16_t* v_sorted = k_sorted + (size_t)B_ * L_ * D_;
    float* q_repr    = (float*)(v_sorted + (size_t)B_ * L_ * D_);
    float* k_repr    = q_repr + (size_t)B_ * H_ * NB_ * HD_;
    float* P         = k_repr + (size_t)B_ * H_ * NB_ * HD_;

    bf16_t* x_bf   = (bf16_t*)d_out;               // d_out scratch until GEMM2
    bf16_t* Wqkv_t = x_bf + (size_t)B_ * L_ * D_;
    bf16_t* Wout_t = (bf16_t*)q_repr;              // dead after sinkhorn

    // 0a. x -> bf16
    f32_to_bf16_kernel<<<(B_ * L_ * D_ / 4 + 255) / 256, 256, 0, stream>>>(
        x, x_bf, B_ * L_ * D_ / 4);
    // 0b. W_qkv [1024,3072] -> Wqkv_t bf16 [3072,1024]
    transpose_f32_bf16_kernel<<<dim3(3 * D_ / 32, D_ / 32), dim3(32, 8), 0, stream>>>(
        W_qkv, Wqkv_t, D_, 3 * D_);

    // 1. QKV projection (MFMA bf16)
    mfma_gemm_bt_kernel<bf16_t>
        <<<dim3(3 * D_ / 128, B_ * L_ / 128), 256, 0, stream>>>(
        x_bf, Wqkv_t, b_qkv, qkv, B_ * L_, 3 * D_, D_);

    // 2. block means
    block_repr_kernel<<<B_ * H_ * NB_, 64, 0, stream>>>(qkv, q_repr, k_repr);

    // 3. Gumbel-Sinkhorn -> P
    sinkhorn_kernel<<<B_ * H_, 64, 0, stream>>>(q_repr, k_repr, gumbel, P);

    // 4. soft-sort K/V blocks
    sort_kv_kernel<<<dim3(16, B_ * H_), 256, 0, stream>>>(P, qkv, k_sorted, v_sorted);

    // 5. block-local attention (MFMA)
    attn_mfma_kernel<<<B_ * H_ * NB_, 256, 0, stream>>>(
        qkv, k_sorted, v_sorted, attn_o);

    // 5b. W_out -> Wout_t bf16 [1024,1024]
    transpose_f32_bf16_kernel<<<dim3(D_ / 32, D_ / 32), dim3(32, 8), 0, stream>>>(
        W_out, Wout_t, D_, D_);

    // 6. output projection (MFMA bf16) -> fp32
    mfma_gemm_bt_kernel<float>
        <<<dim3(D_ / 128, B_ * L_ / 128), 256, 0, stream>>>(
        attn_o, Wout_t, b_out, out, B_ * L_, D_, D_);
}

// Round 7
// 542.951 us; speedup vs baseline: 4.4361x; 1.1560x over previous
//
#include <hip/hip_runtime.h>
#include <cstdint>
#include <cstddef>
#include <cstdio>

#define B_   4
#define L_   4096
#define D_   1024
#define H_   16
#define BS_  64
#define HD_  64
#define NB_  64
#define SCALE_   0.125f
#define INV_TEMP (1.0f/0.7f)

typedef unsigned short bf16_t;

#ifndef __has_builtin
#define __has_builtin(x) 0
#endif
#if __has_builtin(__builtin_amdgcn_global_load_lds)
#define HAS_GLD 1
#else
#define HAS_GLD 0
#endif

#if HAS_GLD
#define GLD16(gp, lp) __builtin_amdgcn_global_load_lds(                        \
    (__attribute__((address_space(1))) void*)(uintptr_t)(gp),                  \
    (__attribute__((address_space(3))) void*)(unsigned int)(uintptr_t)(lp),    \
    16, 0, 0)
#endif

__device__ __forceinline__ float b2f(bf16_t u) {
    union { unsigned int i; float f; } c; c.i = ((unsigned int)u) << 16; return c.f;
}
__device__ __forceinline__ bf16_t f2b(float f) {
    union { float f; unsigned int i; } c; c.f = f;
    unsigned int r = c.i + 0x7FFFu + ((c.i >> 16) & 1u);   // RNE
    return (bf16_t)(r >> 16);
}

__device__ __forceinline__ float4 load4(const float* p) { return *(const float4*)p; }
__device__ __forceinline__ float4 load4(const bf16_t* p) {
    ushort4 u = *(const ushort4*)p;
    return float4{b2f(u.x), b2f(u.y), b2f(u.z), b2f(u.w)};
}
__device__ __forceinline__ void storeC(float* p, float v)  { *p = v; }
__device__ __forceinline__ void storeC(bf16_t* p, float v) { *p = f2b(v); }

using bf16x8 = __attribute__((ext_vector_type(8))) short;
using f32x4  = __attribute__((ext_vector_type(4))) float;

// ---------------------------------------------------------------------------
// fp32 -> bf16 elementwise (4 elems/thread)
// ---------------------------------------------------------------------------
__global__ __launch_bounds__(256) void f32_to_bf16_kernel(
    const float* __restrict__ src, bf16_t* __restrict__ dst, int n4)
{
    const int i = blockIdx.x * 256 + threadIdx.x;
    if (i < n4) {
        float4 v = *(const float4*)(src + (size_t)i * 4);
        ushort4 o = {f2b(v.x), f2b(v.y), f2b(v.z), f2b(v.w)};
        *(ushort4*)(dst + (size_t)i * 4) = o;
    }
}

// ---------------------------------------------------------------------------
// fp32 [R][C] -> bf16 [C][R] transpose (32x32 LDS tile, block 32x8)
// ---------------------------------------------------------------------------
__global__ __launch_bounds__(256) void transpose_f32_bf16_kernel(
    const float* __restrict__ src, bf16_t* __restrict__ dst, int R, int C)
{
    __shared__ float t[32][33];
    const int c0 = blockIdx.x * 32, r0 = blockIdx.y * 32;
    for (int i = threadIdx.y; i < 32; i += 8)
        t[i][threadIdx.x] = src[(size_t)(r0 + i) * C + c0 + threadIdx.x];
    __syncthreads();
    for (int i = threadIdx.y; i < 32; i += 8)
        dst[(size_t)(c0 + i) * R + r0 + threadIdx.x] = f2b(t[threadIdx.x][i]);
}

// ---------------------------------------------------------------------------
// MFMA bf16 GEMM (m97 structure): C[M,N] = A[M,K] @ Bt[N,K]^T + bias[N]
// (verified rounds 5-6)
// ---------------------------------------------------------------------------
template<typename TC>
__global__ __launch_bounds__(256) void mfma_gemm_bt_kernel(
    const bf16_t* __restrict__ A, const bf16_t* __restrict__ Bt,
    const float* __restrict__ bias, TC* __restrict__ C,
    int M, int N, int K)
{
    __shared__ short As_s[128 * 32];
    __shared__ short Bs_s[128 * 32];
    const int tid  = threadIdx.x;
    const int lane = tid & 63;
    const int w    = tid >> 6;
    const int wm   = w >> 1, wn = w & 1;
    const int m0 = blockIdx.y * 128, n0 = blockIdx.x * 128;

    const int srow = 32 * w + (lane >> 2);
    const int scol = (lane & 3) * 8;
    const bf16_t* gA = A  + (size_t)(m0 + srow) * K + scol;
    const bf16_t* gB = Bt + (size_t)(n0 + srow) * K + scol;
    short* lAu = &As_s[(32 * w) * 32];
    short* lBu = &Bs_s[(32 * w) * 32];

    const int ml = lane & 15;
    const int q8 = (lane >> 4) * 8;

    f32x4 acc[4][4];
    #pragma unroll
    for (int i = 0; i < 4; ++i)
        #pragma unroll
        for (int j = 0; j < 4; ++j)
            acc[i][j] = {0.f, 0.f, 0.f, 0.f};

    const int KT = K >> 5;

    auto stage = [&](int kt) {
        const size_t ko = (size_t)kt * 32;
#if HAS_GLD
        GLD16(gA + ko,                lAu);
        GLD16(gA + (size_t)16 * K + ko, lAu + 16 * 32);
        GLD16(gB + ko,                lBu);
        GLD16(gB + (size_t)16 * K + ko, lBu + 16 * 32);
#else
        bf16x8 va0 = *(const bf16x8*)(gA + ko);
        bf16x8 va1 = *(const bf16x8*)(gA + (size_t)16 * K + ko);
        bf16x8 vb0 = *(const bf16x8*)(gB + ko);
        bf16x8 vb1 = *(const bf16x8*)(gB + (size_t)16 * K + ko);
        *(bf16x8*)(lAu + lane * 8)           = va0;
        *(bf16x8*)(lAu + 16 * 32 + lane * 8) = va1;
        *(bf16x8*)(lBu + lane * 8)           = vb0;
        *(bf16x8*)(lBu + 16 * 32 + lane * 8) = vb1;
#endif
    };

    stage(0);
    for (int kt = 0; kt < KT; ++kt) {
        __syncthreads();
        bf16x8 af[4], bfr[4];
        #pragma unroll
        for (int i = 0; i < 4; ++i) {
            af[i]  = *(const bf16x8*)&As_s[(wm * 64 + i * 16 + ml) * 32 + q8];
            bfr[i] = *(const bf16x8*)&Bs_s[(wn * 64 + i * 16 + ml) * 32 + q8];
        }
        #pragma unroll
        for (int i = 0; i < 4; ++i)
            #pragma unroll
            for (int j = 0; j < 4; ++j)
                acc[i][j] = __builtin_amdgcn_mfma_f32_16x16x32_bf16(
                    af[i], bfr[j], acc[i][j], 0, 0, 0);
        __syncthreads();
        if (kt + 1 < KT) stage(kt + 1);
    }

    float bv[4];
    #pragma unroll
    for (int j = 0; j < 4; ++j) bv[j] = bias[n0 + wn * 64 + j * 16 + ml];
    const int r0e = (lane >> 4) * 4;
    #pragma unroll
    for (int i = 0; i < 4; ++i)
        #pragma unroll
        for (int j = 0; j < 4; ++j)
            #pragma unroll
            for (int r = 0; r < 4; ++r) {
                const int row = m0 + wm * 64 + i * 16 + r0e + r;
                const int col = n0 + wn * 64 + j * 16 + ml;
                storeC(&C[(size_t)row * N + col], acc[i][j][r] + bv[j]);
            }
}

// ---------------------------------------------------------------------------
// Block means
// ---------------------------------------------------------------------------
__global__ __launch_bounds__(64) void block_repr_kernel(
    const bf16_t* __restrict__ qkv,
    float* __restrict__ q_repr, float* __restrict__ k_repr)
{
    const int blk = blockIdx.x;
    const int n  = blk & 63;
    const int bh = blk >> 6;
    const int h  = bh & 15, b = bh >> 4;
    const int d  = threadIdx.x;
    const bf16_t* base = qkv + (size_t)(b * L_ + n * BS_) * (3 * D_) + h * HD_ + d;
    float sq = 0.f, sk = 0.f;
    for (int s = 0; s < BS_; ++s) {
        sq += b2f(base[(size_t)s * (3 * D_)]);
        sk += b2f(base[(size_t)s * (3 * D_) + D_]);
    }
    q_repr[(size_t)blk * HD_ + d] = sq * (1.0f / BS_);
    k_repr[(size_t)blk * HD_ + d] = sk * (1.0f / BS_);
}

// ---------------------------------------------------------------------------
// Gumbel-Sinkhorn: one wave per (b,h); P written as bf16 (consumed by the
// MFMA sort kernel).
// ---------------------------------------------------------------------------
__global__ __launch_bounds__(64) void sinkhorn_kernel(
    const float* __restrict__ q_repr, const float* __restrict__ k_repr,
    const float* __restrict__ gumbel, bf16_t* __restrict__ P_bf)
{
    __shared__ float qr[64][65];
    __shared__ float kr[64][65];
    __shared__ float la[64][65];
    const int bh = blockIdx.x;
    const int t  = threadIdx.x;

    for (int i = 0; i < 64; ++i) {
        qr[i][t] = q_repr[((size_t)bh * 64 + i) * 64 + t];
        kr[i][t] = k_repr[((size_t)bh * 64 + i) * 64 + t];
    }
    __syncthreads();

    for (int m = 0; m < 64; ++m) {
        float s = 0.f;
        for (int d = 0; d < 64; ++d) s += qr[t][d] * kr[m][d];
        la[t][m] = (s * SCALE_ + gumbel[((size_t)bh * 64 + t) * 64 + m]) * INV_TEMP;
    }
    __syncthreads();

    for (int it = 0; it < 7; ++it) {
        {
            float mx = -1e30f;
            for (int m = 0; m < 64; ++m) mx = fmaxf(mx, la[t][m]);
            float sum = 0.f;
            for (int m = 0; m < 64; ++m) sum += expf(la[t][m] - mx);
            const float lse = mx + logf(sum);
            for (int m = 0; m < 64; ++m) la[t][m] -= lse;
        }
        __syncthreads();
        {
            float mx = -1e30f;
            for (int m = 0; m < 64; ++m) mx = fmaxf(mx, la[m][t]);
            float sum = 0.f;
            for (int m = 0; m < 64; ++m) sum += expf(la[m][t] - mx);
            const float lse = mx + logf(sum);
            for (int m = 0; m < 64; ++m) la[m][t] -= lse;
        }
        __syncthreads();
    }

    for (int i = 0; i < 64; ++i)
        P_bf[((size_t)bh * 64 + i) * 64 + t] = f2b(expf(la[i][t]));
}

// ---------------------------------------------------------------------------
// MFMA soft-sort: per (b,h): out[n,f] = sum_m P[n,m] * src[m,f], f = s*64+d.
// A = P from LDS (Pl[64][72], 4n-bank stride -> 2-way, free). B-frags read
// DIRECTLY from global: lane ml holds src[m=kt*32+q8+j][f=t*16+ml] — 8 scalar
// ushort loads per frag, quad-coalesced (16 consecutive f = 32 B), each
// element consumed exactly once (no reuse lost). Grid (16 f-chunks, 64 bh),
// wave w covers f in [c*256+w*64, +64); s = c*4+w is wave-uniform.
// ---------------------------------------------------------------------------
__global__ __launch_bounds__(256) void sort_kv_mfma_kernel(
    const bf16_t* __restrict__ P_bf, const bf16_t* __restrict__ qkv,
    bf16_t* __restrict__ k_sorted, bf16_t* __restrict__ v_sorted)
{
    constexpr int TS = 72;
    __shared__ short Pl[64 * TS];
    const int tid = threadIdx.x, lane = tid & 63, w = tid >> 6;
    const int bh = blockIdx.y;
    const int h = bh & 15, b = bh >> 4;
    const int c = blockIdx.x;
    const int ml = lane & 15, q8 = (lane >> 4) * 8;

    // stage P[n][m] -> Pl bf16
    {
        const int r = tid >> 3, cc = (tid & 7) * 8;
        const bf16_t* ps = P_bf + (size_t)bh * (NB_ * NB_);
        *(bf16x8*)&Pl[r * TS + cc]        = *(const bf16x8*)&ps[r * 64 + cc];
        *(bf16x8*)&Pl[(r + 32) * TS + cc] = *(const bf16x8*)&ps[(r + 32) * 64 + cc];
    }
    __syncthreads();

    const int s = c * 4 + w;                       // token index within block
    const int fbase = c * 256 + w * 64;

    for (int kv = 0; kv < 2; ++kv) {
        const bf16_t* src = qkv + ((size_t)(b * L_ + s)) * (3 * D_)
                          + (kv ? 2 * D_ : 1 * D_) + h * HD_;
        // B-frags: bt[t][kt][j] = src[m = kt*32+q8+j][d = t*16+ml]
        bf16x8 bt[4][2];
        #pragma unroll
        for (int t = 0; t < 4; ++t)
            #pragma unroll
            for (int kt = 0; kt < 2; ++kt)
                #pragma unroll
                for (int j = 0; j < 8; ++j)
                    bt[t][kt][j] = (short)src[
                        (size_t)(kt * 32 + q8 + j) * (BS_ * 3 * D_) + t * 16 + ml];

        f32x4 acc[4][4];
        #pragma unroll
        for (int nt = 0; nt < 4; ++nt)
            #pragma unroll
            for (int t = 0; t < 4; ++t)
                acc[nt][t] = {0.f, 0.f, 0.f, 0.f};

        #pragma unroll
        for (int nt = 0; nt < 4; ++nt) {
            bf16x8 a0 = *(const bf16x8*)&Pl[(nt * 16 + ml) * TS + q8];
            bf16x8 a1 = *(const bf16x8*)&Pl[(nt * 16 + ml) * TS + 32 + q8];
            #pragma unroll
            for (int t = 0; t < 4; ++t) {
                acc[nt][t] = __builtin_amdgcn_mfma_f32_16x16x32_bf16(
                    a0, bt[t][0], acc[nt][t], 0, 0, 0);
                acc[nt][t] = __builtin_amdgcn_mfma_f32_16x16x32_bf16(
                    a1, bt[t][1], acc[nt][t], 0, 0, 0);
            }
        }

        // store: n = nt*16 + quad*4 + reg, f = fbase + t*16 + ml
        bf16_t* dst = (kv ? v_sorted : k_sorted) + (size_t)bh * (NB_ * BS_ * HD_);
        const int quad4 = (lane >> 4) * 4;
        #pragma unroll
        for (int nt = 0; nt < 4; ++nt)
            #pragma unroll
            for (int t = 0; t < 4; ++t)
                #pragma unroll
                for (int r = 0; r < 4; ++r)
                    dst[(size_t)(nt * 16 + quad4 + r) * (BS_ * HD_)
                        + fbase + t * 16 + ml] = f2b(acc[nt][t][r]);
    }
}

// ---------------------------------------------------------------------------
// MFMA block attention (verified round 6)
// ---------------------------------------------------------------------------
__global__ __launch_bounds__(256) void attn_mfma_kernel(
    const bf16_t* __restrict__ qkv, const bf16_t* __restrict__ k_sorted,
    const bf16_t* __restrict__ v_sorted, bf16_t* __restrict__ attn_out)
{
    constexpr int KS = 72, VS = 136, PS = 136;
    __shared__ short Ks[128 * KS];
    __shared__ short Vt[64 * VS];
    __shared__ short Psh[64 * PS];
    const int tid = threadIdx.x, lane = tid & 63, w = tid >> 6;
    const int n  = blockIdx.x & 63;
    const int bh = blockIdx.x >> 6;
    const int h = bh & 15, b = bh >> 4;
    const bool last = (n == NB_ - 1);

    const bf16_t* qb = qkv + (size_t)(b * L_ + n * BS_) * (3 * D_) + h * HD_;
    const bf16_t* kb = qb + D_;
    const bf16_t* vb = qb + 2 * D_;
    const size_t nextoff = ((size_t)bh * NB_ + (n + 1)) * (size_t)(BS_ * HD_);
    const bf16_t* kn = k_sorted + nextoff;
    const bf16_t* vn = v_sorted + nextoff;

    {
        const int col8 = (tid & 7) * 8, r0 = tid >> 3;
        const int jjmax = last ? 2 : 4;
        for (int jj = 0; jj < jjmax; ++jj) {
            const int row = jj * 32 + r0;
            const bf16_t* src = (row < 64)
                ? kb + (size_t)row * (3 * D_) + col8
                : kn + (size_t)(row - 64) * HD_ + col8;
            *(bf16x8*)&Ks[row * KS + col8] = *(const bf16x8*)src;
        }
    }
    {
        const int halves = last ? 1 : 2;
        for (int half = 0; half < halves; ++half) {
            for (int jj = 0; jj < 4; ++jj) {
                const int d0 = jj * 16 + w * 4;
                const bf16_t* src = (half == 0)
                    ? vb + (size_t)lane * (3 * D_) + d0
                    : vn + (size_t)lane * HD_ + d0;
                ushort4 u = *(const ushort4*)src;
                const int kcol = half * 64 + lane;
                Vt[(d0 + 0) * VS + kcol] = u.x;
                Vt[(d0 + 1) * VS + kcol] = u.y;
                Vt[(d0 + 2) * VS + kcol] = u.z;
                Vt[(d0 + 3) * VS + kcol] = u.w;
            }
        }
    }

    const int ml = lane & 15, quad = lane >> 4, q8 = quad * 8;
    const int m0 = w * 16;

    bf16x8 af0 = *(const bf16x8*)(qb + (size_t)(m0 + ml) * (3 * D_) + q8);
    bf16x8 af1 = *(const bf16x8*)(qb + (size_t)(m0 + ml) * (3 * D_) + 32 + q8);

    __syncthreads();

    const int ntile = last ? 4 : 8;
    f32x4 st[8];
    #pragma unroll
    for (int t = 0; t < 8; ++t) st[t] = {0.f, 0.f, 0.f, 0.f};
    for (int t = 0; t < ntile; ++t) {
        bf16x8 b0 = *(const bf16x8*)&Ks[(t * 16 + ml) * KS + q8];
        bf16x8 b1 = *(const bf16x8*)&Ks[(t * 16 + ml) * KS + 32 + q8];
        st[t] = __builtin_amdgcn_mfma_f32_16x16x32_bf16(af0, b0, st[t], 0, 0, 0);
        st[t] = __builtin_amdgcn_mfma_f32_16x16x32_bf16(af1, b1, st[t], 0, 0, 0);
    }

    #pragma unroll
    for (int reg = 0; reg < 4; ++reg) {
        float mx = -1e30f;
        for (int t = 0; t < ntile; ++t) mx = fmaxf(mx, st[t][reg] * SCALE_);
        #pragma unroll
        for (int xm = 1; xm <= 8; xm <<= 1)
            mx = fmaxf(mx, __shfl_xor(mx, xm, 64));
        float e[8];
        float sum = 0.f;
        for (int t = 0; t < ntile; ++t) {
            e[t] = __expf(st[t][reg] * SCALE_ - mx);
            sum += e[t];
        }
        #pragma unroll
        for (int xm = 1; xm <= 8; xm <<= 1)
            sum += __shfl_xor(sum, xm, 64);
        const float inv = 1.0f / sum;
        const int qrow = m0 + quad * 4 + reg;
        for (int t = 0; t < ntile; ++t)
            Psh[qrow * PS + t * 16 + ml] = f2b(e[t] * inv);
    }

    __syncthreads();

    const int ktv = last ? 2 : 4;
    f32x4 oacc[4];
    #pragma unroll
    for (int t = 0; t < 4; ++t) oacc[t] = {0.f, 0.f, 0.f, 0.f};
    for (int kt = 0; kt < ktv; ++kt) {
        bf16x8 pa = *(const bf16x8*)&Psh[(m0 + ml) * PS + kt * 32 + q8];
        #pragma unroll
        for (int t = 0; t < 4; ++t) {
            bf16x8 vf = *(const bf16x8*)&Vt[(t * 16 + ml) * VS + kt * 32 + q8];
            oacc[t] = __builtin_amdgcn_mfma_f32_16x16x32_bf16(pa, vf, oacc[t], 0, 0, 0);
        }
    }

    bf16_t* ob = attn_out + (size_t)(b * L_ + n * BS_) * D_ + h * HD_;
    #pragma unroll
    for (int t = 0; t < 4; ++t)
        #pragma unroll
        for (int reg = 0; reg < 4; ++reg) {
            const int qrow = m0 + quad * 4 + reg;
            ob[(size_t)qrow * D_ + t * 16 + ml] = f2b(oacc[t][reg]);
        }
}

// ---------------------------------------------------------------------------
extern "C" void kernel_launch(void* const* d_in, const int* in_sizes, int n_in,
                              void* d_out, int out_size, void* d_ws, size_t ws_size,
                              hipStream_t stream)
{
    const float* x      = (const float*)d_in[0];
    const float* gumbel = (const float*)d_in[1];
    const float* W_qkv  = (const float*)d_in[2];
    const float* b_qkv  = (const float*)d_in[3];
    const float* W_out  = (const float*)d_in[4];
    const float* b_out  = (const float*)d_in[5];
    float* out = (float*)d_out;

    const size_t need = 204472320ull;
    if (ws_size < need) {
        fprintf(stderr, "[kernel_launch] ws_size=%zu < need=%zu — aborting launch\n",
                ws_size, need);
        return;
    }

    bf16_t* qkv      = (bf16_t*)d_ws;
    bf16_t* attn_o   = qkv    + (size_t)B_ * L_ * 3 * D_;
    bf16_t* k_sorted = attn_o + (size_t)B_ * L_ * D_;
    bf16_t* v_sorted = k_sorted + (size_t)B_ * L_ * D_;
    float* q_repr    = (float*)(v_sorted + (size_t)B_ * L_ * D_);
    float* k_repr    = q_repr + (size_t)B_ * H_ * NB_ * HD_;
    bf16_t* P_bf     = (bf16_t*)(k_repr + (size_t)B_ * H_ * NB_ * HD_);

    bf16_t* x_bf   = (bf16_t*)d_out;               // d_out scratch until GEMM2
    bf16_t* Wqkv_t = x_bf + (size_t)B_ * L_ * D_;
    bf16_t* Wout_t = (bf16_t*)q_repr;              // dead after sinkhorn

    // 0a. x -> bf16
    f32_to_bf16_kernel<<<(B_ * L_ * D_ / 4 + 255) / 256, 256, 0, stream>>>(
        x, x_bf, B_ * L_ * D_ / 4);
    // 0b. W_qkv [1024,3072] -> Wqkv_t bf16 [3072,1024]
    transpose_f32_bf16_kernel<<<dim3(3 * D_ / 32, D_ / 32), dim3(32, 8), 0, stream>>>(
        W_qkv, Wqkv_t, D_, 3 * D_);

    // 1. QKV projection (MFMA bf16)
    mfma_gemm_bt_kernel<bf16_t>
        <<<dim3(3 * D_ / 128, B_ * L_ / 128), 256, 0, stream>>>(
        x_bf, Wqkv_t, b_qkv, qkv, B_ * L_, 3 * D_, D_);

    // 2. block means
    block_repr_kernel<<<B_ * H_ * NB_, 64, 0, stream>>>(qkv, q_repr, k_repr);

    // 3. Gumbel-Sinkhorn -> P (bf16)
    sinkhorn_kernel<<<B_ * H_, 64, 0, stream>>>(q_repr, k_repr, gumbel, P_bf);

    // 4. soft-sort K/V blocks (MFMA)
    sort_kv_mfma_kernel<<<dim3(16, B_ * H_), 256, 0, stream>>>(
        P_bf, qkv, k_sorted, v_sorted);

    // 5. block-local attention (MFMA)
    attn_mfma_kernel<<<B_ * H_ * NB_, 256, 0, stream>>>(
        qkv, k_sorted, v_sorted, attn_o);

    // 5b. W_out -> Wout_t bf16 [1024,1024]
    transpose_f32_bf16_kernel<<<dim3(D_ / 32, D_ / 32), dim3(32, 8), 0, stream>>>(
        W_out, Wout_t, D_, D_);

    // 6. output projection (MFMA bf16) -> fp32
    mfma_gemm_bt_kernel<float>
        <<<dim3(D_ / 128, B_ * L_ / 128), 256, 0, stream>>>(
        attn_o, Wout_t, b_out, out, B_ * L_, D_, D_);
}